// Round 8
// baseline (583.985 us; speedup 1.0000x reference)
//
#include <hip/hip_runtime.h>
#include <hip/hip_bf16.h>

// ---------------------------------------------------------------------------
// Bidirectional Mamba block on MI355X (gfx950).  R8 (= R7 with the compile
// fix: __exp2f collided with glibc's internal __exp2f declaration; use
// __builtin_amdgcn_exp2f -> raw v_exp_f32, which IS exp2 on AMD HW).
//
// R7/R8 changes vs R6 (550 us):
//  - Atab stores -exp(A_log)*log2(e); scan exps use hw exp2 directly
//    (saves the v_mul inside every __expf -> ~20% of the scan VALU bundle).
//  - gemm3 tile 128x64 -> 32x64: grid 64 -> 256 blocks (was 75% chip-idle).
//  - conv_silu vectorized 8 d/thread (bf16x8 loads/stores).
//  - cvt kernels float4-vectorized.
// Layout/structure unchanged from R6 (state [(c,b),n,d], fixup parallel).
// ws ~108.3 MiB + 16 MiB cumdt scratch in d_out (proven safe).
// ---------------------------------------------------------------------------

using bf16h = __hip_bfloat16;
typedef __bf16 bf16x8 __attribute__((ext_vector_type(8)));
typedef __bf16 bf16x4 __attribute__((ext_vector_type(4)));
typedef float f32x4 __attribute__((ext_vector_type(4)));

#define BB 4
#define LL 2048
#define DM 512
#define DI 1024
#define DS 16
#define MR (BB * LL)   // 8192 rows
#define NC 64          // scan chunks
#define LC 32          // chunk length
#define LOG2E 1.44269504088896f

#if defined(__has_builtin)
#if __has_builtin(__builtin_amdgcn_exp2f)
#define EXP2F(x) __builtin_amdgcn_exp2f(x)
#else
#define EXP2F(x) exp2f(x)
#endif
#else
#define EXP2F(x) exp2f(x)
#endif

// async global->LDS, 16B per lane; LDS dest is wave-uniform base (+lane*16 by HW)
__device__ __forceinline__ void async_copy16(const void* g, void* l) {
    __builtin_amdgcn_global_load_lds(
        (const __attribute__((address_space(1))) unsigned int*)g,
        (__attribute__((address_space(3))) unsigned int*)l,
        16, 0, 0);
}

// f32 -> bf16, 4 elements/thread (n must be divisible by 4)
__global__ __launch_bounds__(256) void cvt_f32_bf16_v4(
    const float* __restrict__ src, bf16h* __restrict__ dst, int n4)
{
    int i = blockIdx.x * 256 + threadIdx.x;
    if (i >= n4) return;
    f32x4 v = ((const f32x4*)src)[i];
    bf16x4 o;
#pragma unroll
    for (int j = 0; j < 4; ++j) o[j] = (__bf16)v[j];
    ((bf16x4*)dst)[i] = o;
}

// Atab[n*DI + d] = -exp(Alog[d*DS + n]) * log2(e)   (exp2-domain, transposed)
__global__ __launch_bounds__(256) void make_atab(
    const float* __restrict__ Alog, float* __restrict__ Atab)
{
    int i = blockIdx.x * 256 + threadIdx.x;     // over DS*DI
    int d = i & (DI - 1), n = i >> 10;
    Atab[i] = -__expf(Alog[d * DS + n]) * LOG2E;
}

// NT GEMM: C[m][n] = sum_k A[m][k] * B[n][k]; A,B bf16 row-major.
// EPI: 0 = bf16 store OB1 | 1 = f32 store OF1 |
//      2 = split: col<1024 -> OB1 bf16, col>=1024 -> OB2 bf16 (both ld 1024) |
//      3 = softplus(acc + bias[col]) -> bf16 OB1.
template <int BM, int BN, int BK, int WROWS, int WCOLS, int EPI>
__global__ __launch_bounds__(256) void gemm_nt(
    const __bf16* __restrict__ A, const __bf16* __restrict__ B,
    float* __restrict__ OF1, bf16h* __restrict__ OB1, bf16h* __restrict__ OB2,
    const float* __restrict__ bias,
    int K, int lda, int ldb, int ldc)
{
    constexpr int MT  = BM / (16 * WROWS);
    constexpr int NT_ = BN / (16 * WCOLS);
    constexpr int KCH = BK / 8;             // 16B chunks per row
    constexpr int ACH = BM * KCH / 256;
    constexpr int BCH = BN * KCH / 256;
    __shared__ alignas(16) __bf16 As[BM * BK];
    __shared__ alignas(16) __bf16 Bs[BN * BK];

    const int tid  = threadIdx.x, wave = tid >> 6, lane = tid & 63;
    const int quad = lane >> 4, l16 = lane & 15;
    const int wm = wave / WCOLS, wn = wave % WCOLS;
    const int bm0 = blockIdx.y * BM, bn0 = blockIdx.x * BN;

    f32x4 acc[MT][NT_];
#pragma unroll
    for (int i = 0; i < MT; ++i)
#pragma unroll
        for (int j = 0; j < NT_; ++j) acc[i][j] = (f32x4){0.f, 0.f, 0.f, 0.f};

    for (int k0 = 0; k0 < K; k0 += BK) {
#pragma unroll
        for (int i = 0; i < ACH; ++i) {
            int c = i * 256 + wave * 64 + lane;
            int r = c / KCH, cb = c % KCH;
            async_copy16(A + (size_t)(bm0 + r) * lda + k0 + cb * 8,
                         (void*)(As + (size_t)(i * 256 + wave * 64) * 8));
        }
#pragma unroll
        for (int i = 0; i < BCH; ++i) {
            int c = i * 256 + wave * 64 + lane;
            int r = c / KCH, cb = c % KCH;
            async_copy16(B + (size_t)(bn0 + r) * ldb + k0 + cb * 8,
                         (void*)(Bs + (size_t)(i * 256 + wave * 64) * 8));
        }
        __syncthreads();
#pragma unroll
        for (int kk = 0; kk < BK; kk += 32) {
            bf16x8 af[MT], bfv[NT_];
#pragma unroll
            for (int i = 0; i < MT; ++i)
                af[i] = *(const bf16x8*)&As[(wm * MT * 16 + i * 16 + l16) * BK + kk + quad * 8];
#pragma unroll
            for (int j = 0; j < NT_; ++j)
                bfv[j] = *(const bf16x8*)&Bs[(wn * NT_ * 16 + j * 16 + l16) * BK + kk + quad * 8];
#pragma unroll
            for (int i = 0; i < MT; ++i)
#pragma unroll
                for (int j = 0; j < NT_; ++j)
                    acc[i][j] = __builtin_amdgcn_mfma_f32_16x16x32_bf16(af[i], bfv[j], acc[i][j], 0, 0, 0);
        }
        __syncthreads();
    }

#pragma unroll
    for (int i = 0; i < MT; ++i)
#pragma unroll
        for (int j = 0; j < NT_; ++j) {
            int row0 = bm0 + wm * MT * 16 + i * 16 + quad * 4;  // C/D: row = quad*4+reg
            int col  = bn0 + wn * NT_ * 16 + j * 16 + l16;      // C/D: col = lane&15
#pragma unroll
            for (int r = 0; r < 4; ++r) {
                float v = acc[i][j][r];
                int row = row0 + r;
                if constexpr (EPI == 0) {
                    OB1[(size_t)row * ldc + col] = __float2bfloat16(v);
                } else if constexpr (EPI == 1) {
                    OF1[(size_t)row * ldc + col] = v;
                } else if constexpr (EPI == 2) {
                    if (col < 1024) OB1[(size_t)row * 1024 + col] = __float2bfloat16(v);
                    else OB2[(size_t)row * 1024 + (col - 1024)] = __float2bfloat16(v);
                } else {
                    v += bias[col];
                    float sp = (v > 20.f) ? v : log1pf(__expf(v));
                    OB1[(size_t)row * ldc + col] = __float2bfloat16(sp);
                }
            }
        }
}

// depthwise conv + silu on the x-plane, 8 d/thread (bf16x8).
// REV=0: causal w[k]*x[t-3+k]; REV=1: anti-causal w[k]*x[t+3-k].
template <int REV>
__global__ __launch_bounds__(256) void conv_silu(
    const bf16h* __restrict__ xp,
    const float* __restrict__ w, const float* __restrict__ bb,
    bf16h* __restrict__ xc)
{
    int idx = blockIdx.x * 256 + threadIdx.x;   // over MR*DI/8
    int d0 = (idx << 3) & (DI - 1);
    size_t row = (size_t)(idx >> 7);            // DI/8 = 128 threads per row
    int t = (int)(row & (LL - 1));
    int b = (int)(row >> 11);

    float a[8];
#pragma unroll
    for (int j = 0; j < 8; ++j) a[j] = bb[d0 + j];
#pragma unroll
    for (int k = 0; k < 4; ++k) {
        int tt = REV ? (t + 3 - k) : (t - 3 + k);
        if (tt >= 0 && tt < LL) {
            bf16x8 xv = *(const bf16x8*)&xp[(size_t)(b * LL + tt) * DI + d0];
#pragma unroll
            for (int j = 0; j < 8; ++j)
                a[j] += w[(d0 + j) * 4 + k] * (float)xv[j];
        }
    }
    bf16x8 o;
#pragma unroll
    for (int j = 0; j < 8; ++j) {
        float s = a[j] / (1.f + __expf(-a[j]));
        o[j] = (__bf16)s;
    }
    *(bf16x8*)&xc[row * DI + d0] = o;
}

// Pass 1: per-chunk local scan from h=0.  Emits:
//   - chunk-end states (layout [(c,b),n,d] -> coalesced) + sum(dt)
//   - y_part[row,d] = sum_n h_loc[n]*C_n   (bf16, IN-PLACE over dt_y)
//   - cumdt[row,d]  = inclusive prefix of dt within chunk (bf16, d_out scratch)
// Atab is exp2-domain: h *= exp2(dt * Atab[n]).
template <int REV>
__global__ __launch_bounds__(256) void scan_pass1(
    bf16h* dt_y,
    const bf16h* __restrict__ xcp, const bf16h* __restrict__ xdb,
    const float* __restrict__ Atab,
    float* __restrict__ state, float* __restrict__ sumdt,
    bf16h* __restrict__ cumdt)
{
    int c = blockIdx.x, b = blockIdx.y, d = blockIdx.z * 256 + threadIdx.x;
    float Av[DS];
#pragma unroll
    for (int n = 0; n < DS; ++n) Av[n] = Atab[n * DI + d];   // coalesced
    float h[DS];
#pragma unroll
    for (int n = 0; n < DS; ++n) h[n] = 0.f;
    float sdt = 0.f;
    for (int i = 0; i < LC; ++i) {
        int s = c * LC + i;
        int t = REV ? (LL - 1 - s) : s;
        size_t row = (size_t)(b * LL + t);
        size_t rowd = row * DI + d;
        float dtv = __bfloat162float(dt_y[rowd]);
        float xvv = __bfloat162float(xcp[rowd]);
        const bf16h* bc = xdb + row * 64 + 32;   // B_t (row-uniform -> broadcast)
        const bf16h* cc = bc + 16;               // C_t
        float dtx = dtv * xvv;
        sdt += dtv;
        float y = 0.f;
#pragma unroll
        for (int n = 0; n < DS; ++n) {
            h[n] = EXP2F(dtv * Av[n]) * h[n] + dtx * __bfloat162float(bc[n]);
            y += h[n] * __bfloat162float(cc[n]);
        }
        cumdt[rowd] = __float2bfloat16(sdt);
        dt_y[rowd]  = __float2bfloat16(y);       // y_part overwrites dt
    }
    size_t sb = ((size_t)c * BB + b) * DS;
#pragma unroll
    for (int n = 0; n < DS; ++n) state[(sb + n) * DI + d] = h[n];  // coalesced
    sumdt[((size_t)c * BB + b) * DI + d] = sdt;
}

// Pass 2: sequential prefix over chunks; state[c] becomes h_init for chunk c.
__global__ __launch_bounds__(256) void scan_pass2(
    const float* __restrict__ Atab, const float* __restrict__ sumdt,
    float* __restrict__ state)
{
    int gid = blockIdx.x * 256 + threadIdx.x;   // over BB*DS*DI
    int d = gid & (DI - 1), n = (gid >> 10) & (DS - 1), b = gid >> 14;
    float Av = Atab[n * DI + d];
    float carry = 0.f;
    for (int c = 0; c < NC; ++c) {
        size_t si = (((size_t)c * BB + b) * DS + n) * DI + d;
        float hend = state[si];
        float dec  = EXP2F(Av * sumdt[((size_t)c * BB + b) * DI + d]);
        state[si] = carry;
        carry = carry * dec + hend;
    }
}

// Fixup: fully parallel over (row, d).
//   y = (y_part + sum_n h_init[n]*exp2(Av[n]*cumdt)*C_n + D*x) * silu(z)
// REV=0 writes yb; REV=1 accumulates.
template <int REV>
__global__ __launch_bounds__(256) void scan_fixup(
    const bf16h* __restrict__ y_part, const bf16h* __restrict__ cumdt,
    const bf16h* __restrict__ xcp, const bf16h* __restrict__ zp,
    const bf16h* __restrict__ xdb,
    const float* __restrict__ Atab, const float* __restrict__ Dp,
    const float* __restrict__ state, bf16h* __restrict__ yb)
{
    int idx = blockIdx.x * 256 + threadIdx.x;   // (row * DI + d); row uniform per block
    int d = idx & (DI - 1);
    size_t row = (size_t)(idx >> 10);
    int t = (int)(row & (LL - 1));
    int b = (int)(row >> 11);
    int s = REV ? (LL - 1 - t) : t;
    int c = s / LC;

    const bf16h* cc = xdb + row * 64 + 48;       // C_t (row-uniform -> broadcast)
    float cum = __bfloat162float(cumdt[idx]);
    const float* hbase = state + ((size_t)c * BB + b) * DS * DI + d;

    float dy = 0.f;
#pragma unroll
    for (int n = 0; n < DS; ++n) {
        float Av = Atab[n * DI + d];             // coalesced
        float hn = hbase[(size_t)n * DI];        // coalesced
        dy += hn * EXP2F(Av * cum) * __bfloat162float(cc[n]);
    }
    float y = __bfloat162float(y_part[idx]) + dy
            + Dp[d] * __bfloat162float(xcp[idx]);
    float zv = __bfloat162float(zp[idx]);
    float outv = y * zv / (1.f + __expf(-zv));
    if (REV) outv += __bfloat162float(yb[idx]);
    yb[idx] = __float2bfloat16(outv);
}

extern "C" void kernel_launch(void* const* d_in, const int* in_sizes, int n_in,
                              void* d_out, int out_size, void* d_ws, size_t ws_size,
                              hipStream_t stream)
{
    const float* hidden = (const float*)d_in[0];
    const float* W_in   = (const float*)d_in[1];
    const float* W_out  = (const float*)d_in[2];
    const float* cw[2]  = {(const float*)d_in[3],  (const float*)d_in[10]};
    const float* cb[2]  = {(const float*)d_in[4],  (const float*)d_in[11]};
    const float* Wx[2]  = {(const float*)d_in[5],  (const float*)d_in[12]};
    const float* Wdt[2] = {(const float*)d_in[6],  (const float*)d_in[13]};
    const float* bdt[2] = {(const float*)d_in[7],  (const float*)d_in[14]};
    const float* Al[2]  = {(const float*)d_in[8],  (const float*)d_in[15]};
    const float* Dp[2]  = {(const float*)d_in[9],  (const float*)d_in[16]};

    // ---- workspace: ~108.3 MiB, no aliasing ----
    char* ws = (char*)d_ws;
    bf16h* hidden_b = (bf16h*)ws;  ws += (size_t)MR * DM * 2;            // 8 MiB
    bf16h* Wpool    = (bf16h*)ws;  ws += (size_t)2048 * 512 * 2;         // 2 MiB
    bf16h* bufX     = (bf16h*)ws;  ws += (size_t)MR * DI * 2;            // 16 MiB
    bf16h* bufZ     = (bf16h*)ws;  ws += (size_t)MR * DI * 2;            // 16 MiB
    bf16h* xcb      = (bf16h*)ws;  ws += (size_t)MR * DI * 2;            // 16 MiB
    bf16h* xdblb    = (bf16h*)ws;  ws += (size_t)MR * 64 * 2;            // 1 MiB
    bf16h* dtb      = (bf16h*)ws;  ws += (size_t)MR * DI * 2;            // 16 MiB (dt -> y_part)
    float* state    = (float*)ws;  ws += (size_t)NC * BB * DS * DI * 4;  // 16 MiB
    float* sumdt    = (float*)ws;  ws += (size_t)NC * BB * DI * 4;       // 1 MiB
    bf16h* yb       = (bf16h*)ws;  ws += (size_t)MR * DI * 2;            // 16 MiB
    float* Atab     = (float*)ws;  ws += (size_t)DS * DI * 4;            // 64 KiB
    // cumdt scratch lives in d_out (16 MiB, exact fit; overwritten by gemm2)
    bf16h* cumdt = (bf16h*)d_out;

    dim3 blk(256);
    auto cvt = [&](const float* s, bf16h* dst, int n) {
        cvt_f32_bf16_v4<<<dim3(n / 4 / 256 + ((n / 4) % 256 ? 1 : 0)), blk, 0, stream>>>(s, dst, n / 4);
    };

    // 1. xz = hidden @ W_in^T; split X plane / Z plane (both bf16)
    cvt(hidden, hidden_b, MR * DM);
    cvt(W_in, Wpool, 2048 * 512);
    gemm_nt<128, 128, 64, 2, 2, 2><<<dim3(16, 64), blk, 0, stream>>>(
        (const __bf16*)hidden_b, (const __bf16*)Wpool, nullptr, bufX, bufZ,
        nullptr, 512, 512, 512, 1024);

    // 2. per-direction pipelines (stream-serialized, shared buffers)
    for (int dir = 0; dir < 2; ++dir) {
        make_atab<<<dim3(DS * DI / 256), blk, 0, stream>>>(Al[dir], Atab);

        if (dir == 0)
            conv_silu<0><<<dim3(MR * DI / 8 / 256), blk, 0, stream>>>(bufX, cw[0], cb[0], xcb);
        else
            conv_silu<1><<<dim3(MR * DI / 8 / 256), blk, 0, stream>>>(bufX, cw[1], cb[1], xcb);

        // x_dbl = xc @ W_x^T   (N=64, K=1024) -> bf16;  32-row tiles: 256 blocks
        cvt(Wx[dir], Wpool, 64 * DI);
        gemm_nt<32, 64, 64, 2, 2, 0><<<dim3(1, MR / 32), blk, 0, stream>>>(
            (const __bf16*)xcb, (const __bf16*)Wpool, nullptr, xdblb, nullptr,
            nullptr, DI, DI, DI, 64);

        // dt = softplus(dt_r @ W_dt^T + b_dt)   (N=1024, K=32) -> bf16
        cvt(Wdt[dir], Wpool, DI * 32);
        gemm_nt<128, 128, 32, 2, 2, 3><<<dim3(8, 64), blk, 0, stream>>>(
            (const __bf16*)xdblb, (const __bf16*)Wpool, nullptr, dtb, nullptr,
            bdt[dir], 32, 64, 32, DI);

        if (dir == 0) {
            scan_pass1<0><<<dim3(NC, BB, DI / 256), blk, 0, stream>>>(dtb, xcb, xdblb, Atab, state, sumdt, cumdt);
            scan_pass2<<<dim3(BB * DS * DI / 256), blk, 0, stream>>>(Atab, sumdt, state);
            scan_fixup<0><<<dim3(MR * DI / 256), blk, 0, stream>>>(dtb, cumdt, xcb, bufZ, xdblb, Atab, Dp[0], state, yb);
        } else {
            scan_pass1<1><<<dim3(NC, BB, DI / 256), blk, 0, stream>>>(dtb, xcb, xdblb, Atab, state, sumdt, cumdt);
            scan_pass2<<<dim3(BB * DS * DI / 256), blk, 0, stream>>>(Atab, sumdt, state);
            scan_fixup<1><<<dim3(MR * DI / 256), blk, 0, stream>>>(dtb, cumdt, xcb, bufZ, xdblb, Atab, Dp[1], state, yb);
        }
    }

    // 3. out = yb @ W_out^T   (M=8192, N=512, K=1024) -> f32 d_out
    cvt(W_out, Wpool, DM * DI);
    gemm_nt<128, 128, 64, 2, 2, 1><<<dim3(4, 64), blk, 0, stream>>>(
        (const __bf16*)yb, (const __bf16*)Wpool, (float*)d_out, nullptr, nullptr,
        nullptr, DI, DI, DI, DM);
}

// Round 9
// 508.717 us; speedup vs baseline: 1.1480x; 1.1480x over previous
//
#include <hip/hip_runtime.h>
#include <hip/hip_bf16.h>

// ---------------------------------------------------------------------------
// Bidirectional Mamba block on MI355X (gfx950).  R9.
// R8 total 584 us; conv_silu regressed to 64 us x2 because the x8 rewrite
// emitted 32 scalar w-loads/thread with 128B lane stride (64 cache lines per
// instruction -> latency-bound, VALUBusy 7.5%).  R9: w loaded as 8x float4
// (contiguous 128B/thread, coalesced across lanes), bb as 2x float4.
// Everything else identical to R8 (passed, absmax 3.66e-4).
// ---------------------------------------------------------------------------

using bf16h = __hip_bfloat16;
typedef __bf16 bf16x8 __attribute__((ext_vector_type(8)));
typedef __bf16 bf16x4 __attribute__((ext_vector_type(4)));
typedef float f32x4 __attribute__((ext_vector_type(4)));

#define BB 4
#define LL 2048
#define DM 512
#define DI 1024
#define DS 16
#define MR (BB * LL)   // 8192 rows
#define NC 64          // scan chunks
#define LC 32          // chunk length
#define LOG2E 1.44269504088896f

#if defined(__has_builtin)
#if __has_builtin(__builtin_amdgcn_exp2f)
#define EXP2F(x) __builtin_amdgcn_exp2f(x)
#else
#define EXP2F(x) exp2f(x)
#endif
#else
#define EXP2F(x) exp2f(x)
#endif

// async global->LDS, 16B per lane; LDS dest is wave-uniform base (+lane*16 by HW)
__device__ __forceinline__ void async_copy16(const void* g, void* l) {
    __builtin_amdgcn_global_load_lds(
        (const __attribute__((address_space(1))) unsigned int*)g,
        (__attribute__((address_space(3))) unsigned int*)l,
        16, 0, 0);
}

// f32 -> bf16, 4 elements/thread (n must be divisible by 4)
__global__ __launch_bounds__(256) void cvt_f32_bf16_v4(
    const float* __restrict__ src, bf16h* __restrict__ dst, int n4)
{
    int i = blockIdx.x * 256 + threadIdx.x;
    if (i >= n4) return;
    f32x4 v = ((const f32x4*)src)[i];
    bf16x4 o;
#pragma unroll
    for (int j = 0; j < 4; ++j) o[j] = (__bf16)v[j];
    ((bf16x4*)dst)[i] = o;
}

// Atab[n*DI + d] = -exp(Alog[d*DS + n]) * log2(e)   (exp2-domain, transposed)
__global__ __launch_bounds__(256) void make_atab(
    const float* __restrict__ Alog, float* __restrict__ Atab)
{
    int i = blockIdx.x * 256 + threadIdx.x;     // over DS*DI
    int d = i & (DI - 1), n = i >> 10;
    Atab[i] = -__expf(Alog[d * DS + n]) * LOG2E;
}

// NT GEMM: C[m][n] = sum_k A[m][k] * B[n][k]; A,B bf16 row-major.
// EPI: 0 = bf16 store OB1 | 1 = f32 store OF1 |
//      2 = split: col<1024 -> OB1 bf16, col>=1024 -> OB2 bf16 (both ld 1024) |
//      3 = softplus(acc + bias[col]) -> bf16 OB1.
template <int BM, int BN, int BK, int WROWS, int WCOLS, int EPI>
__global__ __launch_bounds__(256) void gemm_nt(
    const __bf16* __restrict__ A, const __bf16* __restrict__ B,
    float* __restrict__ OF1, bf16h* __restrict__ OB1, bf16h* __restrict__ OB2,
    const float* __restrict__ bias,
    int K, int lda, int ldb, int ldc)
{
    constexpr int MT  = BM / (16 * WROWS);
    constexpr int NT_ = BN / (16 * WCOLS);
    constexpr int KCH = BK / 8;             // 16B chunks per row
    constexpr int ACH = BM * KCH / 256;
    constexpr int BCH = BN * KCH / 256;
    __shared__ alignas(16) __bf16 As[BM * BK];
    __shared__ alignas(16) __bf16 Bs[BN * BK];

    const int tid  = threadIdx.x, wave = tid >> 6, lane = tid & 63;
    const int quad = lane >> 4, l16 = lane & 15;
    const int wm = wave / WCOLS, wn = wave % WCOLS;
    const int bm0 = blockIdx.y * BM, bn0 = blockIdx.x * BN;

    f32x4 acc[MT][NT_];
#pragma unroll
    for (int i = 0; i < MT; ++i)
#pragma unroll
        for (int j = 0; j < NT_; ++j) acc[i][j] = (f32x4){0.f, 0.f, 0.f, 0.f};

    for (int k0 = 0; k0 < K; k0 += BK) {
#pragma unroll
        for (int i = 0; i < ACH; ++i) {
            int c = i * 256 + wave * 64 + lane;
            int r = c / KCH, cb = c % KCH;
            async_copy16(A + (size_t)(bm0 + r) * lda + k0 + cb * 8,
                         (void*)(As + (size_t)(i * 256 + wave * 64) * 8));
        }
#pragma unroll
        for (int i = 0; i < BCH; ++i) {
            int c = i * 256 + wave * 64 + lane;
            int r = c / KCH, cb = c % KCH;
            async_copy16(B + (size_t)(bn0 + r) * ldb + k0 + cb * 8,
                         (void*)(Bs + (size_t)(i * 256 + wave * 64) * 8));
        }
        __syncthreads();
#pragma unroll
        for (int kk = 0; kk < BK; kk += 32) {
            bf16x8 af[MT], bfv[NT_];
#pragma unroll
            for (int i = 0; i < MT; ++i)
                af[i] = *(const bf16x8*)&As[(wm * MT * 16 + i * 16 + l16) * BK + kk + quad * 8];
#pragma unroll
            for (int j = 0; j < NT_; ++j)
                bfv[j] = *(const bf16x8*)&Bs[(wn * NT_ * 16 + j * 16 + l16) * BK + kk + quad * 8];
#pragma unroll
            for (int i = 0; i < MT; ++i)
#pragma unroll
                for (int j = 0; j < NT_; ++j)
                    acc[i][j] = __builtin_amdgcn_mfma_f32_16x16x32_bf16(af[i], bfv[j], acc[i][j], 0, 0, 0);
        }
        __syncthreads();
    }

#pragma unroll
    for (int i = 0; i < MT; ++i)
#pragma unroll
        for (int j = 0; j < NT_; ++j) {
            int row0 = bm0 + wm * MT * 16 + i * 16 + quad * 4;  // C/D: row = quad*4+reg
            int col  = bn0 + wn * NT_ * 16 + j * 16 + l16;      // C/D: col = lane&15
#pragma unroll
            for (int r = 0; r < 4; ++r) {
                float v = acc[i][j][r];
                int row = row0 + r;
                if constexpr (EPI == 0) {
                    OB1[(size_t)row * ldc + col] = __float2bfloat16(v);
                } else if constexpr (EPI == 1) {
                    OF1[(size_t)row * ldc + col] = v;
                } else if constexpr (EPI == 2) {
                    if (col < 1024) OB1[(size_t)row * 1024 + col] = __float2bfloat16(v);
                    else OB2[(size_t)row * 1024 + (col - 1024)] = __float2bfloat16(v);
                } else {
                    v += bias[col];
                    float sp = (v > 20.f) ? v : log1pf(__expf(v));
                    OB1[(size_t)row * ldc + col] = __float2bfloat16(sp);
                }
            }
        }
}

// depthwise conv + silu on the x-plane, 8 d/thread.
// w loaded as 8x float4 (contiguous 128B/thread, coalesced across lanes).
// REV=0: causal w[k]*x[t-3+k]; REV=1: anti-causal w[k]*x[t+3-k].
template <int REV>
__global__ __launch_bounds__(256) void conv_silu(
    const bf16h* __restrict__ xp,
    const float* __restrict__ w, const float* __restrict__ bb,
    bf16h* __restrict__ xc)
{
    int idx = blockIdx.x * 256 + threadIdx.x;   // over MR*DI/8
    int d0 = (idx << 3) & (DI - 1);
    size_t row = (size_t)(idx >> 7);            // DI/8 = 128 threads per row
    int t = (int)(row & (LL - 1));
    int b = (int)(row >> 11);

    // coalesced vector loads: w[(d0..d0+7)*4+k] = 32 contiguous floats
    f32x4 wv[8];
#pragma unroll
    for (int j = 0; j < 8; ++j) wv[j] = ((const f32x4*)(w + (size_t)d0 * 4))[j];
    f32x4 b0 = ((const f32x4*)(bb + d0))[0];
    f32x4 b1 = ((const f32x4*)(bb + d0))[1];

    float a[8];
#pragma unroll
    for (int j = 0; j < 4; ++j) { a[j] = b0[j]; a[4 + j] = b1[j]; }
#pragma unroll
    for (int k = 0; k < 4; ++k) {
        int tt = REV ? (t + 3 - k) : (t - 3 + k);
        if (tt >= 0 && tt < LL) {
            bf16x8 xv = *(const bf16x8*)&xp[(size_t)(b * LL + tt) * DI + d0];
#pragma unroll
            for (int j = 0; j < 8; ++j)
                a[j] += wv[j][k] * (float)xv[j];
        }
    }
    bf16x8 o;
#pragma unroll
    for (int j = 0; j < 8; ++j) {
        float s = a[j] / (1.f + __expf(-a[j]));
        o[j] = (__bf16)s;
    }
    *(bf16x8*)&xc[row * DI + d0] = o;
}

// Pass 1: per-chunk local scan from h=0.  Emits:
//   - chunk-end states (layout [(c,b),n,d] -> coalesced) + sum(dt)
//   - y_part[row,d] = sum_n h_loc[n]*C_n   (bf16, IN-PLACE over dt_y)
//   - cumdt[row,d]  = inclusive prefix of dt within chunk (bf16, d_out scratch)
// Atab is exp2-domain: h *= exp2(dt * Atab[n]).
template <int REV>
__global__ __launch_bounds__(256) void scan_pass1(
    bf16h* dt_y,
    const bf16h* __restrict__ xcp, const bf16h* __restrict__ xdb,
    const float* __restrict__ Atab,
    float* __restrict__ state, float* __restrict__ sumdt,
    bf16h* __restrict__ cumdt)
{
    int c = blockIdx.x, b = blockIdx.y, d = blockIdx.z * 256 + threadIdx.x;
    float Av[DS];
#pragma unroll
    for (int n = 0; n < DS; ++n) Av[n] = Atab[n * DI + d];   // coalesced
    float h[DS];
#pragma unroll
    for (int n = 0; n < DS; ++n) h[n] = 0.f;
    float sdt = 0.f;
    for (int i = 0; i < LC; ++i) {
        int s = c * LC + i;
        int t = REV ? (LL - 1 - s) : s;
        size_t row = (size_t)(b * LL + t);
        size_t rowd = row * DI + d;
        float dtv = __bfloat162float(dt_y[rowd]);
        float xvv = __bfloat162float(xcp[rowd]);
        const bf16h* bc = xdb + row * 64 + 32;   // B_t (row-uniform -> broadcast)
        const bf16h* cc = bc + 16;               // C_t
        float dtx = dtv * xvv;
        sdt += dtv;
        float y = 0.f;
#pragma unroll
        for (int n = 0; n < DS; ++n) {
            h[n] = EXP2F(dtv * Av[n]) * h[n] + dtx * __bfloat162float(bc[n]);
            y += h[n] * __bfloat162float(cc[n]);
        }
        cumdt[rowd] = __float2bfloat16(sdt);
        dt_y[rowd]  = __float2bfloat16(y);       // y_part overwrites dt
    }
    size_t sb = ((size_t)c * BB + b) * DS;
#pragma unroll
    for (int n = 0; n < DS; ++n) state[(sb + n) * DI + d] = h[n];  // coalesced
    sumdt[((size_t)c * BB + b) * DI + d] = sdt;
}

// Pass 2: sequential prefix over chunks; state[c] becomes h_init for chunk c.
__global__ __launch_bounds__(256) void scan_pass2(
    const float* __restrict__ Atab, const float* __restrict__ sumdt,
    float* __restrict__ state)
{
    int gid = blockIdx.x * 256 + threadIdx.x;   // over BB*DS*DI
    int d = gid & (DI - 1), n = (gid >> 10) & (DS - 1), b = gid >> 14;
    float Av = Atab[n * DI + d];
    float carry = 0.f;
    for (int c = 0; c < NC; ++c) {
        size_t si = (((size_t)c * BB + b) * DS + n) * DI + d;
        float hend = state[si];
        float dec  = EXP2F(Av * sumdt[((size_t)c * BB + b) * DI + d]);
        state[si] = carry;
        carry = carry * dec + hend;
    }
}

// Fixup: fully parallel over (row, d).
//   y = (y_part + sum_n h_init[n]*exp2(Av[n]*cumdt)*C_n + D*x) * silu(z)
// REV=0 writes yb; REV=1 accumulates.
template <int REV>
__global__ __launch_bounds__(256) void scan_fixup(
    const bf16h* __restrict__ y_part, const bf16h* __restrict__ cumdt,
    const bf16h* __restrict__ xcp, const bf16h* __restrict__ zp,
    const bf16h* __restrict__ xdb,
    const float* __restrict__ Atab, const float* __restrict__ Dp,
    const float* __restrict__ state, bf16h* __restrict__ yb)
{
    int idx = blockIdx.x * 256 + threadIdx.x;   // (row * DI + d); row uniform per block
    int d = idx & (DI - 1);
    size_t row = (size_t)(idx >> 10);
    int t = (int)(row & (LL - 1));
    int b = (int)(row >> 11);
    int s = REV ? (LL - 1 - t) : t;
    int c = s / LC;

    const bf16h* cc = xdb + row * 64 + 48;       // C_t (row-uniform -> broadcast)
    float cum = __bfloat162float(cumdt[idx]);
    const float* hbase = state + ((size_t)c * BB + b) * DS * DI + d;

    float dy = 0.f;
#pragma unroll
    for (int n = 0; n < DS; ++n) {
        float Av = Atab[n * DI + d];             // coalesced
        float hn = hbase[(size_t)n * DI];        // coalesced
        dy += hn * EXP2F(Av * cum) * __bfloat162float(cc[n]);
    }
    float y = __bfloat162float(y_part[idx]) + dy
            + Dp[d] * __bfloat162float(xcp[idx]);
    float zv = __bfloat162float(zp[idx]);
    float outv = y * zv / (1.f + __expf(-zv));
    if (REV) outv += __bfloat162float(yb[idx]);
    yb[idx] = __float2bfloat16(outv);
}

extern "C" void kernel_launch(void* const* d_in, const int* in_sizes, int n_in,
                              void* d_out, int out_size, void* d_ws, size_t ws_size,
                              hipStream_t stream)
{
    const float* hidden = (const float*)d_in[0];
    const float* W_in   = (const float*)d_in[1];
    const float* W_out  = (const float*)d_in[2];
    const float* cw[2]  = {(const float*)d_in[3],  (const float*)d_in[10]};
    const float* cb[2]  = {(const float*)d_in[4],  (const float*)d_in[11]};
    const float* Wx[2]  = {(const float*)d_in[5],  (const float*)d_in[12]};
    const float* Wdt[2] = {(const float*)d_in[6],  (const float*)d_in[13]};
    const float* bdt[2] = {(const float*)d_in[7],  (const float*)d_in[14]};
    const float* Al[2]  = {(const float*)d_in[8],  (const float*)d_in[15]};
    const float* Dp[2]  = {(const float*)d_in[9],  (const float*)d_in[16]};

    // ---- workspace: ~108.3 MiB, no aliasing ----
    char* ws = (char*)d_ws;
    bf16h* hidden_b = (bf16h*)ws;  ws += (size_t)MR * DM * 2;            // 8 MiB
    bf16h* Wpool    = (bf16h*)ws;  ws += (size_t)2048 * 512 * 2;         // 2 MiB
    bf16h* bufX     = (bf16h*)ws;  ws += (size_t)MR * DI * 2;            // 16 MiB
    bf16h* bufZ     = (bf16h*)ws;  ws += (size_t)MR * DI * 2;            // 16 MiB
    bf16h* xcb      = (bf16h*)ws;  ws += (size_t)MR * DI * 2;            // 16 MiB
    bf16h* xdblb    = (bf16h*)ws;  ws += (size_t)MR * 64 * 2;            // 1 MiB
    bf16h* dtb      = (bf16h*)ws;  ws += (size_t)MR * DI * 2;            // 16 MiB (dt -> y_part)
    float* state    = (float*)ws;  ws += (size_t)NC * BB * DS * DI * 4;  // 16 MiB
    float* sumdt    = (float*)ws;  ws += (size_t)NC * BB * DI * 4;       // 1 MiB
    bf16h* yb       = (bf16h*)ws;  ws += (size_t)MR * DI * 2;            // 16 MiB
    float* Atab     = (float*)ws;  ws += (size_t)DS * DI * 4;            // 64 KiB
    // cumdt scratch lives in d_out (16 MiB, exact fit; overwritten by gemm2)
    bf16h* cumdt = (bf16h*)d_out;

    dim3 blk(256);
    auto cvt = [&](const float* s, bf16h* dst, int n) {
        cvt_f32_bf16_v4<<<dim3(n / 4 / 256 + ((n / 4) % 256 ? 1 : 0)), blk, 0, stream>>>(s, dst, n / 4);
    };

    // 1. xz = hidden @ W_in^T; split X plane / Z plane (both bf16)
    cvt(hidden, hidden_b, MR * DM);
    cvt(W_in, Wpool, 2048 * 512);
    gemm_nt<128, 128, 64, 2, 2, 2><<<dim3(16, 64), blk, 0, stream>>>(
        (const __bf16*)hidden_b, (const __bf16*)Wpool, nullptr, bufX, bufZ,
        nullptr, 512, 512, 512, 1024);

    // 2. per-direction pipelines (stream-serialized, shared buffers)
    for (int dir = 0; dir < 2; ++dir) {
        make_atab<<<dim3(DS * DI / 256), blk, 0, stream>>>(Al[dir], Atab);

        if (dir == 0)
            conv_silu<0><<<dim3(MR * DI / 8 / 256), blk, 0, stream>>>(bufX, cw[0], cb[0], xcb);
        else
            conv_silu<1><<<dim3(MR * DI / 8 / 256), blk, 0, stream>>>(bufX, cw[1], cb[1], xcb);

        // x_dbl = xc @ W_x^T   (N=64, K=1024) -> bf16;  32-row tiles: 256 blocks
        cvt(Wx[dir], Wpool, 64 * DI);
        gemm_nt<32, 64, 64, 2, 2, 0><<<dim3(1, MR / 32), blk, 0, stream>>>(
            (const __bf16*)xcb, (const __bf16*)Wpool, nullptr, xdblb, nullptr,
            nullptr, DI, DI, DI, 64);

        // dt = softplus(dt_r @ W_dt^T + b_dt)   (N=1024, K=32) -> bf16
        cvt(Wdt[dir], Wpool, DI * 32);
        gemm_nt<128, 128, 32, 2, 2, 3><<<dim3(8, 64), blk, 0, stream>>>(
            (const __bf16*)xdblb, (const __bf16*)Wpool, nullptr, dtb, nullptr,
            bdt[dir], 32, 64, 32, DI);

        if (dir == 0) {
            scan_pass1<0><<<dim3(NC, BB, DI / 256), blk, 0, stream>>>(dtb, xcb, xdblb, Atab, state, sumdt, cumdt);
            scan_pass2<<<dim3(BB * DS * DI / 256), blk, 0, stream>>>(Atab, sumdt, state);
            scan_fixup<0><<<dim3(MR * DI / 256), blk, 0, stream>>>(dtb, cumdt, xcb, bufZ, xdblb, Atab, Dp[0], state, yb);
        } else {
            scan_pass1<1><<<dim3(NC, BB, DI / 256), blk, 0, stream>>>(dtb, xcb, xdblb, Atab, state, sumdt, cumdt);
            scan_pass2<<<dim3(BB * DS * DI / 256), blk, 0, stream>>>(Atab, sumdt, state);
            scan_fixup<1><<<dim3(MR * DI / 256), blk, 0, stream>>>(dtb, cumdt, xcb, bufZ, xdblb, Atab, Dp[1], state, yb);
        }
    }

    // 3. out = yb @ W_out^T   (M=8192, N=512, K=1024) -> f32 d_out
    cvt(W_out, Wpool, DM * DI);
    gemm_nt<128, 128, 64, 2, 2, 1><<<dim3(4, 64), blk, 0, stream>>>(
        (const __bf16*)yb, (const __bf16*)Wpool, (float*)d_out, nullptr, nullptr,
        nullptr, DI, DI, DI, DM);
}

// Round 10
// 455.785 us; speedup vs baseline: 1.2813x; 1.1161x over previous
//
#include <hip/hip_runtime.h>
#include <hip/hip_bf16.h>

// ---------------------------------------------------------------------------
// Bidirectional Mamba block on MI355X (gfx950).  R10.
// R9 = 509 us. Top: scan_fixup 54 us x2 (VALU 65%), pass1 ~inferred 50 x2.
// R10 changes:
//  - scan_fixup: 4 rows (t..t+3, same chunk) per thread at fixed d ->
//    Atab[16] + state[16] loads + addressing shared across 4 elements.
//    (4-aligned t-groups never cross an LC=32 chunk boundary, fwd or rev.)
//  - scan_pass1: 2 d's per thread (bf16x2 / f32x2 accesses) -> uniform B/C
//    loads and address math amortized 2x; h stays in regs (32 floats).
// Everything else identical to R9 (passed, absmax 3.66e-4).
// ---------------------------------------------------------------------------

using bf16h = __hip_bfloat16;
typedef __bf16 bf16x8 __attribute__((ext_vector_type(8)));
typedef __bf16 bf16x4 __attribute__((ext_vector_type(4)));
typedef __bf16 bf16x2 __attribute__((ext_vector_type(2)));
typedef float f32x4 __attribute__((ext_vector_type(4)));
typedef float f32x2 __attribute__((ext_vector_type(2)));

#define BB 4
#define LL 2048
#define DM 512
#define DI 1024
#define DS 16
#define MR (BB * LL)   // 8192 rows
#define NC 64          // scan chunks
#define LC 32          // chunk length
#define LOG2E 1.44269504088896f

#if defined(__has_builtin)
#if __has_builtin(__builtin_amdgcn_exp2f)
#define EXP2F(x) __builtin_amdgcn_exp2f(x)
#else
#define EXP2F(x) exp2f(x)
#endif
#else
#define EXP2F(x) exp2f(x)
#endif

// async global->LDS, 16B per lane; LDS dest is wave-uniform base (+lane*16 by HW)
__device__ __forceinline__ void async_copy16(const void* g, void* l) {
    __builtin_amdgcn_global_load_lds(
        (const __attribute__((address_space(1))) unsigned int*)g,
        (__attribute__((address_space(3))) unsigned int*)l,
        16, 0, 0);
}

// f32 -> bf16, 4 elements/thread (n must be divisible by 4)
__global__ __launch_bounds__(256) void cvt_f32_bf16_v4(
    const float* __restrict__ src, bf16h* __restrict__ dst, int n4)
{
    int i = blockIdx.x * 256 + threadIdx.x;
    if (i >= n4) return;
    f32x4 v = ((const f32x4*)src)[i];
    bf16x4 o;
#pragma unroll
    for (int j = 0; j < 4; ++j) o[j] = (__bf16)v[j];
    ((bf16x4*)dst)[i] = o;
}

// Atab[n*DI + d] = -exp(Alog[d*DS + n]) * log2(e)   (exp2-domain, transposed)
__global__ __launch_bounds__(256) void make_atab(
    const float* __restrict__ Alog, float* __restrict__ Atab)
{
    int i = blockIdx.x * 256 + threadIdx.x;     // over DS*DI
    int d = i & (DI - 1), n = i >> 10;
    Atab[i] = -__expf(Alog[d * DS + n]) * LOG2E;
}

// NT GEMM: C[m][n] = sum_k A[m][k] * B[n][k]; A,B bf16 row-major.
// EPI: 0 = bf16 store OB1 | 1 = f32 store OF1 |
//      2 = split: col<1024 -> OB1 bf16, col>=1024 -> OB2 bf16 (both ld 1024) |
//      3 = softplus(acc + bias[col]) -> bf16 OB1.
template <int BM, int BN, int BK, int WROWS, int WCOLS, int EPI>
__global__ __launch_bounds__(256) void gemm_nt(
    const __bf16* __restrict__ A, const __bf16* __restrict__ B,
    float* __restrict__ OF1, bf16h* __restrict__ OB1, bf16h* __restrict__ OB2,
    const float* __restrict__ bias,
    int K, int lda, int ldb, int ldc)
{
    constexpr int MT  = BM / (16 * WROWS);
    constexpr int NT_ = BN / (16 * WCOLS);
    constexpr int KCH = BK / 8;             // 16B chunks per row
    constexpr int ACH = BM * KCH / 256;
    constexpr int BCH = BN * KCH / 256;
    __shared__ alignas(16) __bf16 As[BM * BK];
    __shared__ alignas(16) __bf16 Bs[BN * BK];

    const int tid  = threadIdx.x, wave = tid >> 6, lane = tid & 63;
    const int quad = lane >> 4, l16 = lane & 15;
    const int wm = wave / WCOLS, wn = wave % WCOLS;
    const int bm0 = blockIdx.y * BM, bn0 = blockIdx.x * BN;

    f32x4 acc[MT][NT_];
#pragma unroll
    for (int i = 0; i < MT; ++i)
#pragma unroll
        for (int j = 0; j < NT_; ++j) acc[i][j] = (f32x4){0.f, 0.f, 0.f, 0.f};

    for (int k0 = 0; k0 < K; k0 += BK) {
#pragma unroll
        for (int i = 0; i < ACH; ++i) {
            int c = i * 256 + wave * 64 + lane;
            int r = c / KCH, cb = c % KCH;
            async_copy16(A + (size_t)(bm0 + r) * lda + k0 + cb * 8,
                         (void*)(As + (size_t)(i * 256 + wave * 64) * 8));
        }
#pragma unroll
        for (int i = 0; i < BCH; ++i) {
            int c = i * 256 + wave * 64 + lane;
            int r = c / KCH, cb = c % KCH;
            async_copy16(B + (size_t)(bn0 + r) * ldb + k0 + cb * 8,
                         (void*)(Bs + (size_t)(i * 256 + wave * 64) * 8));
        }
        __syncthreads();
#pragma unroll
        for (int kk = 0; kk < BK; kk += 32) {
            bf16x8 af[MT], bfv[NT_];
#pragma unroll
            for (int i = 0; i < MT; ++i)
                af[i] = *(const bf16x8*)&As[(wm * MT * 16 + i * 16 + l16) * BK + kk + quad * 8];
#pragma unroll
            for (int j = 0; j < NT_; ++j)
                bfv[j] = *(const bf16x8*)&Bs[(wn * NT_ * 16 + j * 16 + l16) * BK + kk + quad * 8];
#pragma unroll
            for (int i = 0; i < MT; ++i)
#pragma unroll
                for (int j = 0; j < NT_; ++j)
                    acc[i][j] = __builtin_amdgcn_mfma_f32_16x16x32_bf16(af[i], bfv[j], acc[i][j], 0, 0, 0);
        }
        __syncthreads();
    }

#pragma unroll
    for (int i = 0; i < MT; ++i)
#pragma unroll
        for (int j = 0; j < NT_; ++j) {
            int row0 = bm0 + wm * MT * 16 + i * 16 + quad * 4;  // C/D: row = quad*4+reg
            int col  = bn0 + wn * NT_ * 16 + j * 16 + l16;      // C/D: col = lane&15
#pragma unroll
            for (int r = 0; r < 4; ++r) {
                float v = acc[i][j][r];
                int row = row0 + r;
                if constexpr (EPI == 0) {
                    OB1[(size_t)row * ldc + col] = __float2bfloat16(v);
                } else if constexpr (EPI == 1) {
                    OF1[(size_t)row * ldc + col] = v;
                } else if constexpr (EPI == 2) {
                    if (col < 1024) OB1[(size_t)row * 1024 + col] = __float2bfloat16(v);
                    else OB2[(size_t)row * 1024 + (col - 1024)] = __float2bfloat16(v);
                } else {
                    v += bias[col];
                    float sp = (v > 20.f) ? v : log1pf(__expf(v));
                    OB1[(size_t)row * ldc + col] = __float2bfloat16(sp);
                }
            }
        }
}

// depthwise conv + silu on the x-plane, 8 d/thread.
// w loaded as 8x float4 (contiguous 128B/thread, coalesced across lanes).
// REV=0: causal w[k]*x[t-3+k]; REV=1: anti-causal w[k]*x[t+3-k].
template <int REV>
__global__ __launch_bounds__(256) void conv_silu(
    const bf16h* __restrict__ xp,
    const float* __restrict__ w, const float* __restrict__ bb,
    bf16h* __restrict__ xc)
{
    int idx = blockIdx.x * 256 + threadIdx.x;   // over MR*DI/8
    int d0 = (idx << 3) & (DI - 1);
    size_t row = (size_t)(idx >> 7);            // DI/8 = 128 threads per row
    int t = (int)(row & (LL - 1));
    int b = (int)(row >> 11);

    f32x4 wv[8];
#pragma unroll
    for (int j = 0; j < 8; ++j) wv[j] = ((const f32x4*)(w + (size_t)d0 * 4))[j];
    f32x4 b0 = ((const f32x4*)(bb + d0))[0];
    f32x4 b1 = ((const f32x4*)(bb + d0))[1];

    float a[8];
#pragma unroll
    for (int j = 0; j < 4; ++j) { a[j] = b0[j]; a[4 + j] = b1[j]; }
#pragma unroll
    for (int k = 0; k < 4; ++k) {
        int tt = REV ? (t + 3 - k) : (t - 3 + k);
        if (tt >= 0 && tt < LL) {
            bf16x8 xv = *(const bf16x8*)&xp[(size_t)(b * LL + tt) * DI + d0];
#pragma unroll
            for (int j = 0; j < 8; ++j)
                a[j] += wv[j][k] * (float)xv[j];
        }
    }
    bf16x8 o;
#pragma unroll
    for (int j = 0; j < 8; ++j) {
        float s = a[j] / (1.f + __expf(-a[j]));
        o[j] = (__bf16)s;
    }
    *(bf16x8*)&xc[row * DI + d0] = o;
}

// Pass 1: per-chunk local scan from h=0, TWO d's per thread.
// Emits chunk-end states ([(c,b),n,d] coalesced), sum(dt), y_part (in-place
// over dt_y), cumdt (bf16, d_out scratch).  Atab exp2-domain.
template <int REV>
__global__ __launch_bounds__(256) void scan_pass1(
    bf16h* dt_y,
    const bf16h* __restrict__ xcp, const bf16h* __restrict__ xdb,
    const float* __restrict__ Atab,
    float* __restrict__ state, float* __restrict__ sumdt,
    bf16h* __restrict__ cumdt)
{
    int c = blockIdx.x, b = blockIdx.y;
    int d0 = (blockIdx.z * 256 + threadIdx.x) * 2;
    f32x2 Av[DS];
#pragma unroll
    for (int n = 0; n < DS; ++n) Av[n] = *(const f32x2*)&Atab[n * DI + d0];
    f32x2 h[DS];
#pragma unroll
    for (int n = 0; n < DS; ++n) h[n] = (f32x2){0.f, 0.f};
    f32x2 sdt = (f32x2){0.f, 0.f};
    for (int i = 0; i < LC; ++i) {
        int s = c * LC + i;
        int t = REV ? (LL - 1 - s) : s;
        size_t row = (size_t)(b * LL + t);
        size_t rowd = row * DI + d0;
        bf16x2 dt2 = *(const bf16x2*)&dt_y[rowd];
        bf16x2 xc2 = *(const bf16x2*)&xcp[rowd];
        f32x2 dtv = {(float)dt2[0], (float)dt2[1]};
        f32x2 dtx = {dtv[0] * (float)xc2[0], dtv[1] * (float)xc2[1]};
        const bf16h* bc = xdb + row * 64 + 32;   // B_t (row-uniform)
        const bf16h* cc = bc + 16;               // C_t
        sdt[0] += dtv[0]; sdt[1] += dtv[1];
        f32x2 y = (f32x2){0.f, 0.f};
#pragma unroll
        for (int n = 0; n < DS; ++n) {
            float bn = __bfloat162float(bc[n]);
            float cn = __bfloat162float(cc[n]);
            h[n][0] = EXP2F(dtv[0] * Av[n][0]) * h[n][0] + dtx[0] * bn;
            h[n][1] = EXP2F(dtv[1] * Av[n][1]) * h[n][1] + dtx[1] * bn;
            y[0] += h[n][0] * cn;
            y[1] += h[n][1] * cn;
        }
        bf16x2 cw2; cw2[0] = (__bf16)sdt[0]; cw2[1] = (__bf16)sdt[1];
        *(bf16x2*)&cumdt[rowd] = cw2;
        bf16x2 yw2; yw2[0] = (__bf16)y[0]; yw2[1] = (__bf16)y[1];
        *(bf16x2*)&dt_y[rowd] = yw2;             // y_part overwrites dt
    }
    size_t sb = ((size_t)c * BB + b) * DS;
#pragma unroll
    for (int n = 0; n < DS; ++n)
        *(f32x2*)&state[(sb + n) * DI + d0] = h[n];   // coalesced
    *(f32x2*)&sumdt[((size_t)c * BB + b) * DI + d0] = sdt;
}

// Pass 2: sequential prefix over chunks; state[c] becomes h_init for chunk c.
__global__ __launch_bounds__(256) void scan_pass2(
    const float* __restrict__ Atab, const float* __restrict__ sumdt,
    float* __restrict__ state)
{
    int gid = blockIdx.x * 256 + threadIdx.x;   // over BB*DS*DI
    int d = gid & (DI - 1), n = (gid >> 10) & (DS - 1), b = gid >> 14;
    float Av = Atab[n * DI + d];
    float carry = 0.f;
    for (int c = 0; c < NC; ++c) {
        size_t si = (((size_t)c * BB + b) * DS + n) * DI + d;
        float hend = state[si];
        float dec  = EXP2F(Av * sumdt[((size_t)c * BB + b) * DI + d]);
        state[si] = carry;
        carry = carry * dec + hend;
    }
}

// Fixup: FOUR consecutive rows (same chunk) per thread at fixed d.
// Atab[16] + state[16] loads and addressing shared across the 4 elements.
//   y = (y_part + sum_n h_init[n]*exp2(Av[n]*cumdt)*C_n + D*x) * silu(z)
// REV=0 writes yb; REV=1 accumulates.
template <int REV>
__global__ __launch_bounds__(256) void scan_fixup(
    const bf16h* __restrict__ y_part, const bf16h* __restrict__ cumdt,
    const bf16h* __restrict__ xcp, const bf16h* __restrict__ zp,
    const bf16h* __restrict__ xdb,
    const float* __restrict__ Atab, const float* __restrict__ Dp,
    const float* __restrict__ state, bf16h* __restrict__ yb)
{
    int g = blockIdx.x * 256 + threadIdx.x;     // over MR/4 * DI
    int d = g & (DI - 1);
    int rg = g >> 10;                            // row-group: 4 consecutive t
    int t0 = (rg & (LL / 4 - 1)) * 4;
    int b = rg >> 9;                             // LL/4 = 512 groups per b
    int smin = REV ? (LL - 4 - t0) : t0;         // 4-aligned, same LC-chunk
    int c = smin / LC;

    float Dv = Dp[d];
    const float* hbase = state + ((size_t)c * BB + b) * DS * DI + d;
    float Av[DS], hi[DS];
#pragma unroll
    for (int n = 0; n < DS; ++n) {
        Av[n] = Atab[n * DI + d];                // coalesced, shared over 4 rows
        hi[n] = hbase[(size_t)n * DI];           // coalesced, shared over 4 rows
    }

#pragma unroll
    for (int r = 0; r < 4; ++r) {
        size_t row = (size_t)(b * LL + t0 + r);
        size_t idx = row * DI + d;
        const bf16h* cc = xdb + row * 64 + 48;   // C_t (row-uniform)
        float cum = __bfloat162float(cumdt[idx]);
        float dy = 0.f;
#pragma unroll
        for (int n = 0; n < DS; ++n)
            dy += hi[n] * EXP2F(Av[n] * cum) * __bfloat162float(cc[n]);
        float y = __bfloat162float(y_part[idx]) + dy
                + Dv * __bfloat162float(xcp[idx]);
        float zv = __bfloat162float(zp[idx]);
        float outv = y * zv / (1.f + __expf(-zv));
        if (REV) outv += __bfloat162float(yb[idx]);
        yb[idx] = __float2bfloat16(outv);
    }
}

extern "C" void kernel_launch(void* const* d_in, const int* in_sizes, int n_in,
                              void* d_out, int out_size, void* d_ws, size_t ws_size,
                              hipStream_t stream)
{
    const float* hidden = (const float*)d_in[0];
    const float* W_in   = (const float*)d_in[1];
    const float* W_out  = (const float*)d_in[2];
    const float* cw[2]  = {(const float*)d_in[3],  (const float*)d_in[10]};
    const float* cb[2]  = {(const float*)d_in[4],  (const float*)d_in[11]};
    const float* Wx[2]  = {(const float*)d_in[5],  (const float*)d_in[12]};
    const float* Wdt[2] = {(const float*)d_in[6],  (const float*)d_in[13]};
    const float* bdt[2] = {(const float*)d_in[7],  (const float*)d_in[14]};
    const float* Al[2]  = {(const float*)d_in[8],  (const float*)d_in[15]};
    const float* Dp[2]  = {(const float*)d_in[9],  (const float*)d_in[16]};

    // ---- workspace: ~108.3 MiB, no aliasing ----
    char* ws = (char*)d_ws;
    bf16h* hidden_b = (bf16h*)ws;  ws += (size_t)MR * DM * 2;            // 8 MiB
    bf16h* Wpool    = (bf16h*)ws;  ws += (size_t)2048 * 512 * 2;         // 2 MiB
    bf16h* bufX     = (bf16h*)ws;  ws += (size_t)MR * DI * 2;            // 16 MiB
    bf16h* bufZ     = (bf16h*)ws;  ws += (size_t)MR * DI * 2;            // 16 MiB
    bf16h* xcb      = (bf16h*)ws;  ws += (size_t)MR * DI * 2;            // 16 MiB
    bf16h* xdblb    = (bf16h*)ws;  ws += (size_t)MR * 64 * 2;            // 1 MiB
    bf16h* dtb      = (bf16h*)ws;  ws += (size_t)MR * DI * 2;            // 16 MiB (dt -> y_part)
    float* state    = (float*)ws;  ws += (size_t)NC * BB * DS * DI * 4;  // 16 MiB
    float* sumdt    = (float*)ws;  ws += (size_t)NC * BB * DI * 4;       // 1 MiB
    bf16h* yb       = (bf16h*)ws;  ws += (size_t)MR * DI * 2;            // 16 MiB
    float* Atab     = (float*)ws;  ws += (size_t)DS * DI * 4;            // 64 KiB
    // cumdt scratch lives in d_out (16 MiB, exact fit; overwritten by gemm2)
    bf16h* cumdt = (bf16h*)d_out;

    dim3 blk(256);
    auto cvt = [&](const float* s, bf16h* dst, int n) {
        cvt_f32_bf16_v4<<<dim3(n / 4 / 256 + ((n / 4) % 256 ? 1 : 0)), blk, 0, stream>>>(s, dst, n / 4);
    };

    // 1. xz = hidden @ W_in^T; split X plane / Z plane (both bf16)
    cvt(hidden, hidden_b, MR * DM);
    cvt(W_in, Wpool, 2048 * 512);
    gemm_nt<128, 128, 64, 2, 2, 2><<<dim3(16, 64), blk, 0, stream>>>(
        (const __bf16*)hidden_b, (const __bf16*)Wpool, nullptr, bufX, bufZ,
        nullptr, 512, 512, 512, 1024);

    // 2. per-direction pipelines (stream-serialized, shared buffers)
    for (int dir = 0; dir < 2; ++dir) {
        make_atab<<<dim3(DS * DI / 256), blk, 0, stream>>>(Al[dir], Atab);

        if (dir == 0)
            conv_silu<0><<<dim3(MR * DI / 8 / 256), blk, 0, stream>>>(bufX, cw[0], cb[0], xcb);
        else
            conv_silu<1><<<dim3(MR * DI / 8 / 256), blk, 0, stream>>>(bufX, cw[1], cb[1], xcb);

        // x_dbl = xc @ W_x^T   (N=64, K=1024) -> bf16;  32-row tiles: 256 blocks
        cvt(Wx[dir], Wpool, 64 * DI);
        gemm_nt<32, 64, 64, 2, 2, 0><<<dim3(1, MR / 32), blk, 0, stream>>>(
            (const __bf16*)xcb, (const __bf16*)Wpool, nullptr, xdblb, nullptr,
            nullptr, DI, DI, DI, 64);

        // dt = softplus(dt_r @ W_dt^T + b_dt)   (N=1024, K=32) -> bf16
        cvt(Wdt[dir], Wpool, DI * 32);
        gemm_nt<128, 128, 32, 2, 2, 3><<<dim3(8, 64), blk, 0, stream>>>(
            (const __bf16*)xdblb, (const __bf16*)Wpool, nullptr, dtb, nullptr,
            bdt[dir], 32, 64, 32, DI);

        if (dir == 0) {
            scan_pass1<0><<<dim3(NC, BB, DI / 512), blk, 0, stream>>>(dtb, xcb, xdblb, Atab, state, sumdt, cumdt);
            scan_pass2<<<dim3(BB * DS * DI / 256), blk, 0, stream>>>(Atab, sumdt, state);
            scan_fixup<0><<<dim3(MR / 4 * DI / 256), blk, 0, stream>>>(dtb, cumdt, xcb, bufZ, xdblb, Atab, Dp[0], state, yb);
        } else {
            scan_pass1<1><<<dim3(NC, BB, DI / 512), blk, 0, stream>>>(dtb, xcb, xdblb, Atab, state, sumdt, cumdt);
            scan_pass2<<<dim3(BB * DS * DI / 256), blk, 0, stream>>>(Atab, sumdt, state);
            scan_fixup<1><<<dim3(MR / 4 * DI / 256), blk, 0, stream>>>(dtb, cumdt, xcb, bufZ, xdblb, Atab, Dp[1], state, yb);
        }
    }

    // 3. out = yb @ W_out^T   (M=8192, N=512, K=1024) -> f32 d_out
    cvt(W_out, Wpool, DM * DI);
    gemm_nt<128, 128, 64, 2, 2, 1><<<dim3(4, 64), blk, 0, stream>>>(
        (const __bf16*)yb, (const __bf16*)Wpool, (float*)d_out, nullptr, nullptr,
        nullptr, DI, DI, DI, DM);
}